// Round 1
// baseline (558.674 us; speedup 1.0000x reference)
//
#include <hip/hip_runtime.h>

typedef __attribute__((ext_vector_type(8))) short bf16x8;
typedef __attribute__((ext_vector_type(8))) unsigned short u16x8;
typedef __attribute__((ext_vector_type(4))) float f32x4;

#define NB 8
#define CI 64
#define CO 128
#define HH 256
#define WW 256
#define HP 258
#define WP 258
#define SLIDE 576.0f

__device__ __forceinline__ unsigned short f2bf(float f) {
  union { float f; unsigned int u; } c; c.f = f;
  unsigned int u = c.u;
  return (unsigned short)((u + 0x7FFFu + ((u >> 16) & 1u)) >> 16);
}

// K1: W (co,ci,kh,kw) f32 -> Wb [kh][kw][co][ci] bf16
__global__ void k_prepw(const float* __restrict__ W, unsigned short* __restrict__ Wb) {
  int i = blockIdx.x * 256 + threadIdx.x;
  if (i >= 9 * CO * CI) return;
  int ci = i & 63, co = (i >> 6) & 127, tap = i >> 13;
  int kh = tap / 3, kw = tap - 3 * (tap / 3);
  Wb[i] = f2bf(W[((co * CI + ci) * 3 + kh) * 3 + kw]);
}

// K2: xm = bf16(x*mask) into zero-padded NHWC [n][h+1][w+1][ci]; msum = sum_ci mask
__global__ void k_xm(const float4* __restrict__ x4, const float4* __restrict__ m4,
                     unsigned short* __restrict__ xm, float4* __restrict__ msum4) {
  int p4 = blockIdx.x * 256 + threadIdx.x;        // 131072 total (4 pixels each)
  int w4 = p4 & 63, h = (p4 >> 6) & 255, n = p4 >> 14;
  size_t base = (size_t)n * CI * 16384 + (size_t)h * 64 + w4;   // float4 units
  size_t dstb = (((size_t)n * HP + h + 1) * WP + (w4 * 4 + 1)) * CI;
  float4 s = make_float4(0.f, 0.f, 0.f, 0.f);
  for (int cg = 0; cg < 8; ++cg) {
    u16x8 v0, v1, v2, v3;
#pragma unroll
    for (int j = 0; j < 8; ++j) {
      size_t o = base + (size_t)(cg * 8 + j) * 16384;
      float4 xv = x4[o], mv = m4[o];
      s.x += mv.x; s.y += mv.y; s.z += mv.z; s.w += mv.w;
      v0[j] = f2bf(xv.x * mv.x); v1[j] = f2bf(xv.y * mv.y);
      v2[j] = f2bf(xv.z * mv.z); v3[j] = f2bf(xv.w * mv.w);
    }
    *(u16x8*)(xm + dstb + 0 * CI + cg * 8) = v0;
    *(u16x8*)(xm + dstb + 1 * CI + cg * 8) = v1;
    *(u16x8*)(xm + dstb + 2 * CI + cg * 8) = v2;
    *(u16x8*)(xm + dstb + 3 * CI + cg * 8) = v3;
  }
  msum4[p4] = s;
}

// K3: 3x3 box sum of msum -> ratio (= mask_ratio*clip) and updc (= clip(update,0,1))
__global__ void k_update(const float* __restrict__ msum, float* __restrict__ ratio,
                         float* __restrict__ updc) {
  int pix = blockIdx.x * 256 + threadIdx.x;
  int w = pix & 255, h = (pix >> 8) & 255, n = pix >> 16;
  float s = 0.f;
#pragma unroll
  for (int dh = -1; dh <= 1; ++dh) {
    int hh = h + dh;
    if ((unsigned)hh < 256u) {
      const float* row = msum + ((size_t)n * HH + hh) * WW;
#pragma unroll
      for (int dw = -1; dw <= 1; ++dw) {
        int ww = w + dw;
        if ((unsigned)ww < 256u) s += row[ww];
      }
    }
  }
  float uc = fminf(s, 1.0f);
  float rs = SLIDE / (s + 1e-6f) * uc;
  ratio[pix] = rs;
  updc[pix] = uc;
}

// K4: implicit-GEMM conv. Block = 128 px (w-strip) x 128 cout, 4 waves (2m x 2n),
// each wave 64 px x 64 cout via 4x4 grid of 16x16x32 bf16 MFMA fragments.
__global__ __launch_bounds__(256) void k_conv(
    const unsigned short* __restrict__ xm, const unsigned short* __restrict__ Wb,
    const float* __restrict__ ratio, const float* __restrict__ updc,
    const float* __restrict__ bias, float* __restrict__ preBN,
    float* __restrict__ psum, float* __restrict__ psq) {
  __shared__ __align__(16) unsigned short lds_in[3 * 130 * 64];   // 49,920 B
  int b = blockIdx.x;
  int wt = b & 1, h = (b >> 1) & 255, n = b >> 9;
  int w0 = wt * 128;
  int t = threadIdx.x;
  char* ldsc = (char*)lds_in;
  // stage padded rows h..h+2 (unpadded h-1..h+1), padded w0..w0+129, all ci. XOR-swizzled.
  for (int r = 0; r < 3; ++r) {
    size_t srow = (((size_t)n * HP + h + r) * WP + w0) * CI;
    for (int c = t; c < 1040; c += 256) {
      u16x8 v = *(const u16x8*)(xm + srow + (size_t)c * 8);
      int wslot = c >> 3;
      int baddr = (((r * 130 + wslot) << 7) + ((c & 7) << 4)) ^ ((wslot & 7) << 4);
      *(u16x8*)(ldsc + baddr) = v;
    }
  }
  __syncthreads();

  int lane = t & 63, wave = t >> 6;
  int wm = wave >> 1, wn = wave & 1;
  int l15 = lane & 15, l4 = lane >> 4;
  f32x4 zero = {0.f, 0.f, 0.f, 0.f};
  f32x4 acc[4][4];
#pragma unroll
  for (int i = 0; i < 4; ++i)
#pragma unroll
    for (int j = 0; j < 4; ++j) acc[i][j] = zero;

#pragma unroll
  for (int kh = 0; kh < 3; ++kh) {
#pragma unroll
    for (int kw = 0; kw < 3; ++kw) {
      const unsigned short* wtap = Wb + ((kh * 3 + kw) * CO + wn * 64) * CI;
#pragma unroll
      for (int ks = 0; ks < 2; ++ks) {
        bf16x8 af[4], bfr[4];
#pragma unroll
        for (int mf = 0; mf < 4; ++mf) {
          int wslot = wm * 64 + mf * 16 + l15 + kw;
          int baddr = (((kh * 130 + wslot) << 7) + ks * 64 + l4 * 16) ^ ((wslot & 7) << 4);
          af[mf] = *(const bf16x8*)(ldsc + baddr);
        }
#pragma unroll
        for (int nf = 0; nf < 4; ++nf)
          bfr[nf] = *(const bf16x8*)(wtap + (nf * 16 + l15) * CI + ks * 32 + l4 * 8);
#pragma unroll
        for (int mf = 0; mf < 4; ++mf)
#pragma unroll
          for (int nf = 0; nf < 4; ++nf)
            acc[mf][nf] = __builtin_amdgcn_mfma_f32_16x16x32_bf16(af[mf], bfr[nf], acc[mf][nf], 0, 0, 0);
      }
    }
  }

  // epilogue: preBN = conv*ratio + bias*updc, NHWC store; per-channel partial sums
  int pixbase = (n * HH + h) * WW + w0;
  float bv[4];
#pragma unroll
  for (int nf = 0; nf < 4; ++nf) bv[nf] = bias[wn * 64 + nf * 16 + l15];
  float rs_s[4] = {0.f, 0.f, 0.f, 0.f}, rq_s[4] = {0.f, 0.f, 0.f, 0.f};
#pragma unroll
  for (int mf = 0; mf < 4; ++mf) {
#pragma unroll
    for (int r2 = 0; r2 < 4; ++r2) {
      int pi = wm * 64 + mf * 16 + l4 * 4 + r2;
      float rs = ratio[pixbase + pi];
      float uc = updc[pixbase + pi];
      float* prow = preBN + (size_t)(pixbase + pi) * CO;
#pragma unroll
      for (int nf = 0; nf < 4; ++nf) {
        float v = acc[mf][nf][r2] * rs + bv[nf] * uc;
        prow[wn * 64 + nf * 16 + l15] = v;
        rs_s[nf] += v;
        rq_s[nf] += v * v;
      }
    }
  }
  __syncthreads();   // all waves done reading lds_in; reuse as reduction scratch
  float* sred = (float*)lds_in;    // [wave][nf][16] sums, +256 sumsq
#pragma unroll
  for (int nf = 0; nf < 4; ++nf) {
    float s = rs_s[nf], q = rq_s[nf];
    s += __shfl_xor(s, 16); s += __shfl_xor(s, 32);
    q += __shfl_xor(q, 16); q += __shfl_xor(q, 32);
    if (l4 == 0) {
      sred[(wave * 4 + nf) * 16 + l15] = s;
      sred[256 + (wave * 4 + nf) * 16 + l15] = q;
    }
  }
  __syncthreads();
  int co = t & 127;
  int wn2 = co >> 6, nf2 = (co >> 4) & 3, cc = co & 15;
  float a0 = sred[(wn2 * 4 + nf2) * 16 + cc] + sred[((2 + wn2) * 4 + nf2) * 16 + cc];
  float a1 = sred[256 + (wn2 * 4 + nf2) * 16 + cc] + sred[256 + ((2 + wn2) * 4 + nf2) * 16 + cc];
  if (t < 128) psum[(size_t)co * 4096 + b] = a0;
  else         psq[(size_t)co * 4096 + b]  = a1;
}

// K5: reduce partials -> bn scale/shift
__global__ void k_bnstats(const float* __restrict__ psum, const float* __restrict__ psq,
                          const float* __restrict__ gamma, const float* __restrict__ beta,
                          float* __restrict__ bn_scale, float* __restrict__ bn_shift) {
  int co = blockIdx.x;
  int t = threadIdx.x;
  float s = 0.f, q = 0.f;
  for (int i = t; i < 4096; i += 256) {
    s += psum[(size_t)co * 4096 + i];
    q += psq[(size_t)co * 4096 + i];
  }
#pragma unroll
  for (int o = 1; o < 64; o <<= 1) { s += __shfl_xor(s, o); q += __shfl_xor(q, o); }
  __shared__ float red[8];
  int wv = t >> 6, ln = t & 63;
  if (ln == 0) { red[wv] = s; red[4 + wv] = q; }
  __syncthreads();
  if (t == 0) {
    s = red[0] + red[1] + red[2] + red[3];
    q = red[4] + red[5] + red[6] + red[7];
    const float inv = 1.0f / 524288.0f;
    float mean = s * inv;
    float var = q * inv - mean * mean;
    float sc = gamma[co] * rsqrtf(var + 1e-5f);
    bn_scale[co] = sc;
    bn_shift[co] = beta[co] - mean * sc;
  }
}

// K6: preBN (NHWC) -> BN+ReLU -> out (NCHW) via LDS transpose
__global__ __launch_bounds__(256) void k_fin(const float4* __restrict__ pre4,
                                             const float* __restrict__ bn_scale,
                                             const float* __restrict__ bn_shift,
                                             float* __restrict__ out) {
  __shared__ __align__(16) float tile[64 * 132];
  int b = blockIdx.x;
  int wt = b & 3, h = (b >> 2) & 255, n = b >> 10;
  int w0 = wt * 64;
  int t = threadIdx.x;
  size_t pixbase = ((size_t)n * HH + h) * WW + w0;
  int c4 = t & 31;
  float4 sc = ((const float4*)bn_scale)[c4];
  float4 sh = ((const float4*)bn_shift)[c4];
  for (int i = t; i < 2048; i += 256) {
    int pix = i >> 5;
    float4 v = pre4[(pixbase + pix) * 32 + c4];
    v.x = fmaxf(v.x * sc.x + sh.x, 0.f);
    v.y = fmaxf(v.y * sc.y + sh.y, 0.f);
    v.z = fmaxf(v.z * sc.z + sh.z, 0.f);
    v.w = fmaxf(v.w * sc.w + sh.w, 0.f);
    *(float4*)&tile[pix * 132 + c4 * 4] = v;
  }
  __syncthreads();
  int c = t >> 1, half = t & 1;
  float* dst = out + (((size_t)n * CO + c) * HH + h) * WW + w0 + half * 32;
#pragma unroll
  for (int j = 0; j < 8; ++j) {
    float4 v;
    v.x = tile[(half * 32 + j * 4 + 0) * 132 + c];
    v.y = tile[(half * 32 + j * 4 + 1) * 132 + c];
    v.z = tile[(half * 32 + j * 4 + 2) * 132 + c];
    v.w = tile[(half * 32 + j * 4 + 3) * 132 + c];
    *(float4*)(dst + j * 4) = v;
  }
}

// K7: broadcast updc (N,H,W) to update_full (N,CO,H,W)
__global__ void k_updfull(const float4* __restrict__ u4, float4* __restrict__ o4) {
  size_t i = (size_t)blockIdx.x * 256 + threadIdx.x;   // 16,777,216 float4s
  int w4 = (int)(i & 63);
  int h = (int)((i >> 6) & 255);
  int n = (int)(i >> 21);
  o4[i] = u4[((size_t)n << 14) + (h << 6) + w4];
}

extern "C" void kernel_launch(void* const* d_in, const int* in_sizes, int n_in,
                              void* d_out, int out_size, void* d_ws, size_t ws_size,
                              hipStream_t stream) {
  (void)in_sizes; (void)n_in; (void)out_size; (void)ws_size;
  const float* x     = (const float*)d_in[0];
  const float* mask  = (const float*)d_in[1];
  const float* W     = (const float*)d_in[2];
  const float* bias  = (const float*)d_in[3];
  const float* gamma = (const float*)d_in[4];
  const float* beta  = (const float*)d_in[5];

  float* out = (float*)d_out;                          // region1: 67,108,864 f32
  float* upd_out = out + 67108864;                     // region2: 67,108,864 f32
  unsigned short* xm = (unsigned short*)d_out;         // region1 scratch: 68,153,344 B
  float* preBN = upd_out;                              // region2 scratch (f32 NHWC)
  float* part_sum = (float*)((char*)d_out + 134217728);// region1 @ +128MB: 2 MB
  float* part_sq  = part_sum + 524288;                 // +2 MB

  char* wsb = (char*)d_ws;
  unsigned short* Wb = (unsigned short*)wsb;           // 147,456 B
  float* msum  = (float*)(wsb + 147456);               // 2 MB
  float* ratio = (float*)(wsb + 147456 + 2097152);     // 2 MB
  float* updc  = (float*)(wsb + 147456 + 2 * 2097152); // 2 MB
  float* bn_scale = (float*)(wsb + 147456 + 3 * 2097152);
  float* bn_shift = bn_scale + 128;

  // zero padded-xm buffer (borders must be 0)
  hipMemsetAsync(d_out, 0, (size_t)8 * 258 * 258 * 64 * 2, stream);

  k_prepw<<<288, 256, 0, stream>>>(W, Wb);
  k_xm<<<512, 256, 0, stream>>>((const float4*)x, (const float4*)mask, xm, (float4*)msum);
  k_update<<<2048, 256, 0, stream>>>(msum, ratio, updc);
  k_conv<<<4096, 256, 0, stream>>>(xm, Wb, ratio, updc, bias, preBN, part_sum, part_sq);
  k_bnstats<<<128, 256, 0, stream>>>(part_sum, part_sq, gamma, beta, bn_scale, bn_shift);
  k_fin<<<8192, 256, 0, stream>>>((const float4*)preBN, bn_scale, bn_shift, out);
  k_updfull<<<65536, 256, 0, stream>>>((const float4*)updc, (float4*)upd_out);
}

// Round 2
// 498.775 us; speedup vs baseline: 1.1201x; 1.1201x over previous
//
#include <hip/hip_runtime.h>

typedef __attribute__((ext_vector_type(8))) short bf16x8;
typedef __attribute__((ext_vector_type(8))) unsigned short u16x8;
typedef __attribute__((ext_vector_type(4))) float f32x4;

#define NB 8
#define CI 64
#define CO 128
#define HH 256
#define WW 256
#define HP 258
#define WP 258
#define SLIDE 576.0f

__device__ __forceinline__ unsigned short f2bf(float f) {
  union { float f; unsigned int u; } c; c.f = f;
  unsigned int u = c.u;
  return (unsigned short)((u + 0x7FFFu + ((u >> 16) & 1u)) >> 16);
}
__device__ __forceinline__ float bf2f(unsigned short h) {
  union { unsigned int u; float f; } c; c.u = ((unsigned int)h) << 16;
  return c.f;
}

// K0: zero only the pad borders of the xm buffer (interior fully overwritten by k_xm)
__global__ void k_border(unsigned short* __restrict__ xm) {
  int i = blockIdx.x * 256 + threadIdx.x;   // 8 n * 1028 border pixels
  if (i >= 8 * 1028) return;
  int n = i / 1028, p = i - n * 1028;
  int hh, wp;
  if (p < 258) { hh = 0; wp = p; }
  else if (p < 516) { hh = 257; wp = p - 258; }
  else { int q = p - 516; hh = 1 + (q >> 1); wp = (q & 1) * 257; }
  u16x8 z = {0, 0, 0, 0, 0, 0, 0, 0};
  unsigned short* d = xm + (((size_t)n * HP + hh) * WP + wp) * CI;
#pragma unroll
  for (int k = 0; k < 8; ++k) *(u16x8*)(d + k * 8) = z;
}

// K1: W (co,ci,kh,kw) f32 -> Wb [kh][kw][co][ci] bf16
__global__ void k_prepw(const float* __restrict__ W, unsigned short* __restrict__ Wb) {
  int i = blockIdx.x * 256 + threadIdx.x;
  if (i >= 9 * CO * CI) return;
  int ci = i & 63, co = (i >> 6) & 127, tap = i >> 13;
  int kh = tap / 3, kw = tap - 3 * (tap / 3);
  Wb[i] = f2bf(W[((co * CI + ci) * 3 + kh) * 3 + kw]);
}

// K2: xm = bf16(x*mask) into zero-padded NHWC [n][h+1][w+1][ci]; msum = sum_ci mask
__global__ void k_xm(const float4* __restrict__ x4, const float4* __restrict__ m4,
                     unsigned short* __restrict__ xm, float4* __restrict__ msum4) {
  int p4 = blockIdx.x * 256 + threadIdx.x;        // 131072 total (4 pixels each)
  int w4 = p4 & 63, h = (p4 >> 6) & 255, n = p4 >> 14;
  size_t base = (size_t)n * CI * 16384 + (size_t)h * 64 + w4;   // float4 units
  size_t dstb = (((size_t)n * HP + h + 1) * WP + (w4 * 4 + 1)) * CI;
  float4 s = make_float4(0.f, 0.f, 0.f, 0.f);
  for (int cg = 0; cg < 8; ++cg) {
    u16x8 v0, v1, v2, v3;
#pragma unroll
    for (int j = 0; j < 8; ++j) {
      size_t o = base + (size_t)(cg * 8 + j) * 16384;
      float4 xv = x4[o], mv = m4[o];
      s.x += mv.x; s.y += mv.y; s.z += mv.z; s.w += mv.w;
      v0[j] = f2bf(xv.x * mv.x); v1[j] = f2bf(xv.y * mv.y);
      v2[j] = f2bf(xv.z * mv.z); v3[j] = f2bf(xv.w * mv.w);
    }
    *(u16x8*)(xm + dstb + 0 * CI + cg * 8) = v0;
    *(u16x8*)(xm + dstb + 1 * CI + cg * 8) = v1;
    *(u16x8*)(xm + dstb + 2 * CI + cg * 8) = v2;
    *(u16x8*)(xm + dstb + 3 * CI + cg * 8) = v3;
  }
  msum4[p4] = s;
}

// K3: 3x3 box sum of msum -> ratio (= mask_ratio*clip) and updc (= clip(update,0,1))
__global__ void k_update(const float* __restrict__ msum, float* __restrict__ ratio,
                         float* __restrict__ updc) {
  int pix = blockIdx.x * 256 + threadIdx.x;
  int w = pix & 255, h = (pix >> 8) & 255, n = pix >> 16;
  float s = 0.f;
#pragma unroll
  for (int dh = -1; dh <= 1; ++dh) {
    int hh = h + dh;
    if ((unsigned)hh < 256u) {
      const float* row = msum + ((size_t)n * HH + hh) * WW;
#pragma unroll
      for (int dw = -1; dw <= 1; ++dw) {
        int ww = w + dw;
        if ((unsigned)ww < 256u) s += row[ww];
      }
    }
  }
  float uc = fminf(s, 1.0f);
  float rs = SLIDE / (s + 1e-6f) * uc;
  ratio[pix] = rs;
  updc[pix] = uc;
}

// K4: implicit-GEMM conv. Block = 128 px (w-strip) x 128 cout, 4 waves (2m x 2n),
// each wave 64 px x 64 cout via 4x4 grid of 16x16x32 bf16 MFMA fragments.
// Epilogue: bf16 preBN tile staged in LDS, streamed out coalesced (NHWC blob).
__global__ __launch_bounds__(256) void k_conv(
    const unsigned short* __restrict__ xm, const unsigned short* __restrict__ Wb,
    const float* __restrict__ ratio, const float* __restrict__ updc,
    const float* __restrict__ bias, unsigned short* __restrict__ blob,
    float* __restrict__ psum, float* __restrict__ psq) {
  __shared__ __align__(16) char lds[49920];   // staging 49920B; reused: tile 34816 + sred 2048
  int b = blockIdx.x;
  // XCD swizzle: each XCD gets one image n, h-contiguous -> row reuse in per-XCD L2
  int work = (b & 7) * 512 + (b >> 3);
  int wt = work & 1, h = (work >> 1) & 255, n = work >> 9;
  int w0 = wt * 128;
  int t = threadIdx.x;
  // stage padded rows h..h+2, padded cols w0..w0+129, all ci. XOR-swizzled layout.
  for (int r = 0; r < 3; ++r) {
    size_t srow = (((size_t)n * HP + h + r) * WP + w0) * CI;
    for (int c = t; c < 1040; c += 256) {
      u16x8 v = *(const u16x8*)(xm + srow + (size_t)c * 8);
      int wslot = c >> 3;
      int baddr = (((r * 130 + wslot) << 7) + ((c & 7) << 4)) ^ ((wslot & 7) << 4);
      *(u16x8*)(lds + baddr) = v;
    }
  }
  __syncthreads();

  int lane = t & 63, wave = t >> 6;
  int wm = wave >> 1, wn = wave & 1;
  int l15 = lane & 15, l4 = lane >> 4;
  f32x4 zero = {0.f, 0.f, 0.f, 0.f};
  f32x4 acc[4][4];
#pragma unroll
  for (int i = 0; i < 4; ++i)
#pragma unroll
    for (int j = 0; j < 4; ++j) acc[i][j] = zero;

#pragma unroll
  for (int kh = 0; kh < 3; ++kh) {
#pragma unroll
    for (int kw = 0; kw < 3; ++kw) {
      const unsigned short* wtap = Wb + ((kh * 3 + kw) * CO + wn * 64) * CI;
#pragma unroll
      for (int ks = 0; ks < 2; ++ks) {
        bf16x8 af[4], bfr[4];
#pragma unroll
        for (int mf = 0; mf < 4; ++mf) {
          int wslot = wm * 64 + mf * 16 + l15 + kw;
          int baddr = (((kh * 130 + wslot) << 7) + ks * 64 + l4 * 16) ^ ((wslot & 7) << 4);
          af[mf] = *(const bf16x8*)(lds + baddr);
        }
#pragma unroll
        for (int nf = 0; nf < 4; ++nf)
          bfr[nf] = *(const bf16x8*)(wtap + (nf * 16 + l15) * CI + ks * 32 + l4 * 8);
#pragma unroll
        for (int mf = 0; mf < 4; ++mf)
#pragma unroll
          for (int nf = 0; nf < 4; ++nf)
            acc[mf][nf] = __builtin_amdgcn_mfma_f32_16x16x32_bf16(af[mf], bfr[nf], acc[mf][nf], 0, 0, 0);
      }
    }
  }
  __syncthreads();   // everyone done reading staged input; reuse LDS for output tile

  // epilogue: v = conv*ratio + bias*updc; round to bf16; stats from rounded value.
  // tile layout: [pix 0..127] rows of 272 bytes (128 co * 2B + 16B pad)
  int pixbase = (n * HH + h) * WW + w0;
  float bv[4];
#pragma unroll
  for (int nf = 0; nf < 4; ++nf) bv[nf] = bias[wn * 64 + nf * 16 + l15];
  float rs_s[4] = {0.f, 0.f, 0.f, 0.f}, rq_s[4] = {0.f, 0.f, 0.f, 0.f};
#pragma unroll
  for (int mf = 0; mf < 4; ++mf) {
#pragma unroll
    for (int r2 = 0; r2 < 4; ++r2) {
      int pi = wm * 64 + mf * 16 + l4 * 4 + r2;
      float rs = ratio[pixbase + pi];
      float uc = updc[pixbase + pi];
#pragma unroll
      for (int nf = 0; nf < 4; ++nf) {
        float v = acc[mf][nf][r2] * rs + bv[nf] * uc;
        unsigned short h16 = f2bf(v);
        float vr = bf2f(h16);
        rs_s[nf] += vr;
        rq_s[nf] += vr * vr;
        int co = wn * 64 + nf * 16 + l15;
        *(unsigned short*)(lds + pi * 272 + co * 2) = h16;
      }
    }
  }
  // per-channel partial reduce (over l4) into sred
  float* sred = (float*)(lds + 34816);   // 512 floats
#pragma unroll
  for (int nf = 0; nf < 4; ++nf) {
    float s = rs_s[nf], q = rq_s[nf];
    s += __shfl_xor(s, 16); s += __shfl_xor(s, 32);
    q += __shfl_xor(q, 16); q += __shfl_xor(q, 32);
    if (l4 == 0) {
      sred[(wave * 4 + nf) * 16 + l15] = s;
      sred[256 + (wave * 4 + nf) * 16 + l15] = q;
    }
  }
  __syncthreads();
  // coalesced blob store: 128 px * 128 co bf16
  for (int i = t; i < 2048; i += 256) {
    int pix = i >> 4, cg = i & 15;
    u16x8 v = *(const u16x8*)(lds + pix * 272 + cg * 16);
    *(u16x8*)(blob + ((size_t)(pixbase + pix) << 7) + cg * 8) = v;
  }
  int co = t & 127;
  int wn2 = co >> 6, nf2 = (co >> 4) & 3, cc = co & 15;
  float a0 = sred[(wn2 * 4 + nf2) * 16 + cc] + sred[((2 + wn2) * 4 + nf2) * 16 + cc];
  float a1 = sred[256 + (wn2 * 4 + nf2) * 16 + cc] + sred[256 + ((2 + wn2) * 4 + nf2) * 16 + cc];
  if (t < 128) psum[(size_t)co * 4096 + b] = a0;
  else         psq[(size_t)co * 4096 + b]  = a1;
}

// K5: reduce partials -> bn scale/shift
__global__ void k_bnstats(const float* __restrict__ psum, const float* __restrict__ psq,
                          const float* __restrict__ gamma, const float* __restrict__ beta,
                          float* __restrict__ bn_scale, float* __restrict__ bn_shift) {
  int co = blockIdx.x;
  int t = threadIdx.x;
  float s = 0.f, q = 0.f;
  for (int i = t; i < 4096; i += 256) {
    s += psum[(size_t)co * 4096 + i];
    q += psq[(size_t)co * 4096 + i];
  }
#pragma unroll
  for (int o = 1; o < 64; o <<= 1) { s += __shfl_xor(s, o); q += __shfl_xor(q, o); }
  __shared__ float red[8];
  int wv = t >> 6, ln = t & 63;
  if (ln == 0) { red[wv] = s; red[4 + wv] = q; }
  __syncthreads();
  if (t == 0) {
    s = red[0] + red[1] + red[2] + red[3];
    q = red[4] + red[5] + red[6] + red[7];
    const float inv = 1.0f / 524288.0f;
    float mean = s * inv;
    float var = q * inv - mean * mean;
    float sc = gamma[co] * rsqrtf(var + 1e-5f);
    bn_scale[co] = sc;
    bn_shift[co] = beta[co] - mean * sc;
  }
}

// K6: blob (bf16 NHWC) -> BN+ReLU -> out (f32 NCHW) via XOR-swizzled LDS transpose
__global__ __launch_bounds__(256) void k_fin(const unsigned short* __restrict__ blob,
                                             const float* __restrict__ bn_scale,
                                             const float* __restrict__ bn_shift,
                                             float* __restrict__ out) {
  __shared__ __align__(16) float tile[64 * 132];
  int b = blockIdx.x;
  int wt = b & 3, h = (b >> 2) & 255, n = b >> 10;
  int w0 = wt * 64;
  int t = threadIdx.x;
  size_t pixbase = ((size_t)n * HH + h) * WW + w0;
  const float4* s4 = (const float4*)bn_scale;
  const float4* h4 = (const float4*)bn_shift;
  for (int i = t; i < 1024; i += 256) {
    int pix = i >> 4, cg = i & 15;
    u16x8 v = *(const u16x8*)(blob + ((pixbase + pix) << 7) + cg * 8);
    float4 sa = s4[cg * 2], sb = s4[cg * 2 + 1];
    float4 ha = h4[cg * 2], hb = h4[cg * 2 + 1];
    float4 o0, o1;
    o0.x = fmaxf(bf2f(v[0]) * sa.x + ha.x, 0.f);
    o0.y = fmaxf(bf2f(v[1]) * sa.y + ha.y, 0.f);
    o0.z = fmaxf(bf2f(v[2]) * sa.z + ha.z, 0.f);
    o0.w = fmaxf(bf2f(v[3]) * sa.w + ha.w, 0.f);
    o1.x = fmaxf(bf2f(v[4]) * sb.x + hb.x, 0.f);
    o1.y = fmaxf(bf2f(v[5]) * sb.y + hb.y, 0.f);
    o1.z = fmaxf(bf2f(v[6]) * sb.z + hb.z, 0.f);
    o1.w = fmaxf(bf2f(v[7]) * sb.w + hb.w, 0.f);
    int key = (pix & 7) << 2;
    *(float4*)&tile[pix * 132 + ((cg * 8) ^ key)]     = o0;
    *(float4*)&tile[pix * 132 + ((cg * 8 + 4) ^ key)] = o1;
  }
  __syncthreads();
  int wq = t & 15, cc = t >> 4;
#pragma unroll
  for (int i8 = 0; i8 < 8; ++i8) {
    int c = cc + (i8 << 4);
    float4 v;
#pragma unroll
    for (int k = 0; k < 4; ++k) {
      int w = wq * 4 + k;
      ((float*)&v)[k] = tile[w * 132 + (c ^ ((w & 7) << 2))];
    }
    *(float4*)(out + (((size_t)n * CO + c) * HH + h) * WW + w0 + wq * 4) = v;
  }
}

// K7: broadcast updc (N,H,W) to update_full (N,CO,H,W)
__global__ void k_updfull(const float4* __restrict__ u4, float4* __restrict__ o4) {
  size_t base = (size_t)blockIdx.x * 1024 + threadIdx.x;
#pragma unroll
  for (int k = 0; k < 4; ++k) {
    size_t i = base + (size_t)k * 256;    // 16,777,216 float4s total
    int w4 = (int)(i & 63);
    int h = (int)((i >> 6) & 255);
    int n = (int)(i >> 21);
    o4[i] = u4[((size_t)n << 14) + ((size_t)h << 6) + w4];
  }
}

extern "C" void kernel_launch(void* const* d_in, const int* in_sizes, int n_in,
                              void* d_out, int out_size, void* d_ws, size_t ws_size,
                              hipStream_t stream) {
  (void)in_sizes; (void)n_in; (void)out_size; (void)ws_size;
  const float* x     = (const float*)d_in[0];
  const float* mask  = (const float*)d_in[1];
  const float* W     = (const float*)d_in[2];
  const float* bias  = (const float*)d_in[3];
  const float* gamma = (const float*)d_in[4];
  const float* beta  = (const float*)d_in[5];

  float* out = (float*)d_out;                          // region1: 64M f32 (256 MiB)
  float* upd_out = out + 67108864;                     // region2: 64M f32 (256 MiB)
  unsigned short* xm = (unsigned short*)d_out;         // region1 scratch: 68 MB
  unsigned short* blob = (unsigned short*)upd_out;     // region2 scratch: 134 MB bf16 NHWC
  float* part_sum = (float*)((char*)d_out + 134217728);// region1 @ +128MiB: 2 MB
  float* part_sq  = part_sum + 524288;                 // +2 MB

  char* wsb = (char*)d_ws;
  unsigned short* Wb = (unsigned short*)wsb;           // 147,456 B
  float* msum  = (float*)(wsb + 147456);               // 2 MB
  float* ratio = (float*)(wsb + 147456 + 2097152);     // 2 MB
  float* updc  = (float*)(wsb + 147456 + 2 * 2097152); // 2 MB
  float* bn_scale = (float*)(wsb + 147456 + 3 * 2097152);
  float* bn_shift = bn_scale + 128;

  k_border<<<33, 256, 0, stream>>>(xm);
  k_prepw<<<288, 256, 0, stream>>>(W, Wb);
  k_xm<<<512, 256, 0, stream>>>((const float4*)x, (const float4*)mask, xm, (float4*)msum);
  k_update<<<2048, 256, 0, stream>>>(msum, ratio, updc);
  k_conv<<<4096, 256, 0, stream>>>(xm, Wb, ratio, updc, bias, blob, part_sum, part_sq);
  k_bnstats<<<128, 256, 0, stream>>>(part_sum, part_sq, gamma, beta, bn_scale, bn_shift);
  k_fin<<<8192, 256, 0, stream>>>(blob, bn_scale, bn_shift, out);
  k_updfull<<<16384, 256, 0, stream>>>((const float4*)updc, (float4*)upd_out);
}

// Round 3
// 401.613 us; speedup vs baseline: 1.3911x; 1.2419x over previous
//
#include <hip/hip_runtime.h>

typedef __attribute__((ext_vector_type(8))) short bf16x8;
typedef __attribute__((ext_vector_type(8))) unsigned short u16x8;
typedef __attribute__((ext_vector_type(4))) float f32x4;
typedef unsigned int u32;

#define CI 64
#define CO 128
#define HH 256
#define WW 256
#define HP 258
#define WP 258
#define SLIDE 576.0f

__device__ __forceinline__ unsigned short f2bf(float f) {
  union { float f; unsigned int u; } c; c.f = f;
  unsigned int u = c.u;
  return (unsigned short)((u + 0x7FFFu + ((u >> 16) & 1u)) >> 16);
}
__device__ __forceinline__ float bf2f(unsigned short h) {
  union { unsigned int u; float f; } c; c.u = ((unsigned int)h) << 16;
  return c.f;
}

// K_prep: blocks 0..287 transpose W -> Wb [kh][kw][co][ci] bf16; blocks 288.. zero xm borders
__global__ void k_prep(const float* __restrict__ W, unsigned short* __restrict__ Wb,
                       unsigned short* __restrict__ xm) {
  int blk = blockIdx.x, t = threadIdx.x;
  if (blk < 288) {
    int i = blk * 256 + t;            // exactly 9*128*64 = 73728
    int ci = i & 63, co = (i >> 6) & 127, tap = i >> 13;
    int kh = tap / 3, kw = tap - 3 * (tap / 3);
    Wb[i] = f2bf(W[((co * CI + ci) * 3 + kh) * 3 + kw]);
  } else {
    int i = (blk - 288) * 256 + t;    // 8 n * 1028 border pixels
    if (i >= 8 * 1028) return;
    int n = i / 1028, p = i - n * 1028;
    int hh, wp;
    if (p < 258) { hh = 0; wp = p; }
    else if (p < 516) { hh = 257; wp = p - 258; }
    else { int q = p - 516; hh = 1 + (q >> 1); wp = (q & 1) * 257; }
    u16x8 z = {0, 0, 0, 0, 0, 0, 0, 0};
    unsigned short* d = xm + (((size_t)n * HP + hh) * WP + wp) * CI;
#pragma unroll
    for (int k = 0; k < 8; ++k) *(u16x8*)(d + k * 8) = z;
  }
}

// K_xm: xm = bf16(x*mask) -> padded NHWC via LDS transpose (coalesced both sides);
// msum = sum_ci mask. Block = 64px strip x 64 ch for one (n,h).
__global__ __launch_bounds__(256) void k_xm(const float4* __restrict__ x4,
                                            const float4* __restrict__ m4,
                                            unsigned short* __restrict__ xm,
                                            float4* __restrict__ msum4) {
  __shared__ __align__(16) float tile[64 * 64 + 256];   // 16 KB tile + 1 KB reduce
  int b = blockIdx.x;                                    // 8192: wt(4) h(256) n(8)
  int wt = b & 3, h = (b >> 2) & 255, n = b >> 10;
  int w0 = wt * 64;
  int t = threadIdx.x;
  int p4 = t & 15, chg = t >> 4;                         // px-quad, ch-group(4)
  size_t base = (size_t)n * CI * 16384 + (size_t)h * 64 + (w0 >> 2) + p4;
  float4 ms = {0.f, 0.f, 0.f, 0.f};
#pragma unroll
  for (int j = 0; j < 4; ++j) {
    int ch = chg * 4 + j;
    size_t o = base + (size_t)ch * 16384;
    float4 xv = x4[o], mv = m4[o];
    ms.x += mv.x; ms.y += mv.y; ms.z += mv.z; ms.w += mv.w;
    float4 pr;
    pr.x = xv.x * mv.x; pr.y = xv.y * mv.y; pr.z = xv.z * mv.z; pr.w = xv.w * mv.w;
    int kk = (ch >> 3) & 3;                              // XOR key (bits 2-3 of px idx)
    *(float4*)&tile[ch * 64 + ((p4 * 4) ^ (kk << 2))] = pr;
  }
  // reduce mask-sum over the wave's 4 ch-groups (lane bits 4,5)
  ms.x += __shfl_xor(ms.x, 16); ms.y += __shfl_xor(ms.y, 16);
  ms.z += __shfl_xor(ms.z, 16); ms.w += __shfl_xor(ms.w, 16);
  ms.x += __shfl_xor(ms.x, 32); ms.y += __shfl_xor(ms.y, 32);
  ms.z += __shfl_xor(ms.z, 32); ms.w += __shfl_xor(ms.w, 32);
  int wave = t >> 6, lane = t & 63;
  float4* red = (float4*)&tile[4096];
  if (lane < 16) red[wave * 16 + lane] = ms;
  __syncthreads();
  // output: 512 chunks (px 0..63, cg 0..7): 1KB-contiguous global writes per wave
  size_t dstb = (((size_t)n * HP + h + 1) * WP + (w0 + 1)) * CI;
#pragma unroll
  for (int iter = 0; iter < 2; ++iter) {
    int c = iter * 256 + t;
    int px = c >> 3, cg = c & 7;
    u16x8 v;
#pragma unroll
    for (int e = 0; e < 8; ++e) {
      int ch = cg * 8 + e;
      int kk = (ch >> 3) & 3;
      v[e] = f2bf(tile[ch * 64 + (px ^ (kk << 2))]);
    }
    *(u16x8*)(xm + dstb + (size_t)px * CI + cg * 8) = v;
  }
  if (t < 16) {
    float4 a = red[t], b2 = red[16 + t], c2 = red[32 + t], d2 = red[48 + t];
    float4 s;
    s.x = a.x + b2.x + c2.x + d2.x; s.y = a.y + b2.y + c2.y + d2.y;
    s.z = a.z + b2.z + c2.z + d2.z; s.w = a.w + b2.w + c2.w + d2.w;
    msum4[(size_t)n * 16384 + (size_t)h * 64 + (w0 >> 2) + t] = s;
  }
}

// K_update: 3x3 box sum of msum -> ratio (= mask_ratio*clip) and updc (= clip)
__global__ void k_update(const float* __restrict__ msum, float* __restrict__ ratio,
                         float* __restrict__ updc) {
  int pix = blockIdx.x * 256 + threadIdx.x;
  int w = pix & 255, h = (pix >> 8) & 255, n = pix >> 16;
  float s = 0.f;
#pragma unroll
  for (int dh = -1; dh <= 1; ++dh) {
    int hh = h + dh;
    if ((unsigned)hh < 256u) {
      const float* row = msum + ((size_t)n * HH + hh) * WW;
#pragma unroll
      for (int dw = -1; dw <= 1; ++dw) {
        int ww = w + dw;
        if ((unsigned)ww < 256u) s += row[ww];
      }
    }
  }
  float uc = fminf(s, 1.0f);
  float rs = SLIDE / (s + 1e-6f) * uc;
  ratio[pix] = rs;
  updc[pix] = uc;
}

// K_conv: implicit-GEMM 3x3 conv, 128px x 128co per block, 4 waves, 16x16x32 bf16 MFMA.
// Staging via global_load_lds (pre-swizzled global source, linear LDS dest).
__global__ __launch_bounds__(256) void k_conv(
    const unsigned short* __restrict__ xm, const unsigned short* __restrict__ Wb,
    const float* __restrict__ ratio, const float* __restrict__ updc,
    const float* __restrict__ bias, unsigned short* __restrict__ blob,
    float* __restrict__ psum, float* __restrict__ psq) {
  __shared__ __align__(16) char lds[50944];  // 49920 staging (reused) + 1024 ratio/updc
  int b = blockIdx.x;
  // XCD swizzle: each XCD owns one image n, h-contiguous -> row reuse in its L2
  int work = (b & 7) * 512 + (b >> 3);
  int wt = work & 1, h = (work >> 1) & 255, n = work >> 9;
  int w0 = wt * 128;
  int t = threadIdx.x;
  int lane = t & 63, wave = t >> 6;
  float* lr = (float*)(lds + 49920);
  float* lu = (float*)(lds + 50432);
  int pixbase = (n * HH + h) * WW + w0;
  if (t < 128) { lr[t] = ratio[pixbase + t]; lu[t] = updc[pixbase + t]; }
  // stage 3 padded rows x 130 px x 64ch = 3120 16B chunks, swizzled source addr
#pragma unroll
  for (int iter = 0; iter < 12; ++iter) {
    int c = iter * 256 + t;
    int r = (c >= 2080) ? 2 : (c >= 1040 ? 1 : 0);
    int cc = c - r * 1040;
    int wslot = cc >> 3, sub = cc & 7;
    int srcc = (wslot << 3) + (sub ^ (wslot & 7));
    const unsigned short* g = xm + (((size_t)n * HP + h + r) * WP + w0) * CI + (size_t)srcc * 8;
    u32 ldsoff = (u32)(r * 16640 + (((iter * 256 + (wave << 6)) - r * 1040) << 4));
    __builtin_amdgcn_global_load_lds((const __attribute__((address_space(1))) u32*)g,
        (__attribute__((address_space(3))) u32*)(void*)(lds + ldsoff), 16, 0, 0);
  }
  if (t < 48) {   // tail: chunks 3072..3119 (all r=2), wave 0 only
    int c = 3072 + t;
    int cc = c - 2080;
    int wslot = cc >> 3, sub = cc & 7;
    int srcc = (wslot << 3) + (sub ^ (wslot & 7));
    const unsigned short* g = xm + (((size_t)n * HP + h + 2) * WP + w0) * CI + (size_t)srcc * 8;
    u32 ldsoff = (u32)(2 * 16640 + ((3072 - 2080) << 4));
    __builtin_amdgcn_global_load_lds((const __attribute__((address_space(1))) u32*)g,
        (__attribute__((address_space(3))) u32*)(void*)(lds + ldsoff), 16, 0, 0);
  }
  __syncthreads();

  int wm = wave >> 1, wn = wave & 1;
  int l15 = lane & 15, l4 = lane >> 4;
  f32x4 zero = {0.f, 0.f, 0.f, 0.f};
  f32x4 acc[4][4];
#pragma unroll
  for (int i = 0; i < 4; ++i)
#pragma unroll
    for (int j = 0; j < 4; ++j) acc[i][j] = zero;

#pragma unroll
  for (int kh = 0; kh < 3; ++kh) {
#pragma unroll
    for (int kw = 0; kw < 3; ++kw) {
      const unsigned short* wtap = Wb + ((kh * 3 + kw) * CO + wn * 64) * CI;
#pragma unroll
      for (int ks = 0; ks < 2; ++ks) {
        bf16x8 af[4], bfr[4];
#pragma unroll
        for (int mf = 0; mf < 4; ++mf) {
          int wslot = wm * 64 + mf * 16 + l15 + kw;
          int baddr = (((kh * 130 + wslot) << 7) + ks * 64 + l4 * 16) ^ ((wslot & 7) << 4);
          af[mf] = *(const bf16x8*)(lds + baddr);
        }
#pragma unroll
        for (int nf = 0; nf < 4; ++nf)
          bfr[nf] = *(const bf16x8*)(wtap + (nf * 16 + l15) * CI + ks * 32 + l4 * 8);
#pragma unroll
        for (int mf = 0; mf < 4; ++mf)
#pragma unroll
          for (int nf = 0; nf < 4; ++nf)
            acc[mf][nf] = __builtin_amdgcn_mfma_f32_16x16x32_bf16(af[mf], bfr[nf], acc[mf][nf], 0, 0, 0);
      }
    }
  }
  __syncthreads();   // staging area free for reuse as output tile

  float bv[4];
#pragma unroll
  for (int nf = 0; nf < 4; ++nf) bv[nf] = bias[wn * 64 + nf * 16 + l15];
  float rs_s[4] = {0.f, 0.f, 0.f, 0.f}, rq_s[4] = {0.f, 0.f, 0.f, 0.f};
#pragma unroll
  for (int mf = 0; mf < 4; ++mf) {
#pragma unroll
    for (int r2 = 0; r2 < 4; ++r2) {
      int pi = wm * 64 + mf * 16 + l4 * 4 + r2;
      float rs = lr[pi];
      float uc = lu[pi];
#pragma unroll
      for (int nf = 0; nf < 4; ++nf) {
        float v = acc[mf][nf][r2] * rs + bv[nf] * uc;
        unsigned short h16 = f2bf(v);
        float vr = bf2f(h16);
        rs_s[nf] += vr;
        rq_s[nf] += vr * vr;
        int co = wn * 64 + nf * 16 + l15;
        *(unsigned short*)(lds + pi * 272 + co * 2) = h16;
      }
    }
  }
  float* sred = (float*)(lds + 34816);   // 512 floats
#pragma unroll
  for (int nf = 0; nf < 4; ++nf) {
    float s = rs_s[nf], q = rq_s[nf];
    s += __shfl_xor(s, 16); s += __shfl_xor(s, 32);
    q += __shfl_xor(q, 16); q += __shfl_xor(q, 32);
    if (l4 == 0) {
      sred[(wave * 4 + nf) * 16 + l15] = s;
      sred[256 + (wave * 4 + nf) * 16 + l15] = q;
    }
  }
  __syncthreads();
  for (int i = t; i < 2048; i += 256) {
    int pix = i >> 4, cg = i & 15;
    u16x8 v = *(const u16x8*)(lds + pix * 272 + cg * 16);
    *(u16x8*)(blob + ((size_t)(pixbase + pix) << 7) + cg * 8) = v;
  }
  int co = t & 127;
  int wn2 = co >> 6, nf2 = (co >> 4) & 3, cc2 = co & 15;
  float a0 = sred[(wn2 * 4 + nf2) * 16 + cc2] + sred[((2 + wn2) * 4 + nf2) * 16 + cc2];
  float a1 = sred[256 + (wn2 * 4 + nf2) * 16 + cc2] + sred[256 + ((2 + wn2) * 4 + nf2) * 16 + cc2];
  if (t < 128) psum[(size_t)b * 128 + co] = a0;    // contiguous per-block
  else         psq[(size_t)b * 128 + co]  = a1;
}

// K_bnstats: reduce partials -> bn scale/shift
__global__ void k_bnstats(const float* __restrict__ psum, const float* __restrict__ psq,
                          const float* __restrict__ gamma, const float* __restrict__ beta,
                          float* __restrict__ bn_scale, float* __restrict__ bn_shift) {
  int co = blockIdx.x;
  int t = threadIdx.x;
  float s = 0.f, q = 0.f;
  for (int i = t; i < 4096; i += 256) {
    s += psum[(size_t)i * 128 + co];
    q += psq[(size_t)i * 128 + co];
  }
#pragma unroll
  for (int o = 1; o < 64; o <<= 1) { s += __shfl_xor(s, o); q += __shfl_xor(q, o); }
  __shared__ float red[8];
  int wv = t >> 6, ln = t & 63;
  if (ln == 0) { red[wv] = s; red[4 + wv] = q; }
  __syncthreads();
  if (t == 0) {
    s = red[0] + red[1] + red[2] + red[3];
    q = red[4] + red[5] + red[6] + red[7];
    const float inv = 1.0f / 524288.0f;
    float mean = s * inv;
    float var = q * inv - mean * mean;
    float sc = gamma[co] * rsqrtf(var + 1e-5f);
    bn_scale[co] = sc;
    bn_shift[co] = beta[co] - mean * sc;
  }
}

// K_out: blob (bf16 NHWC) -> BN+ReLU -> out (f32 NCHW) AND update_full broadcast,
// fused, via XOR-swizzled LDS transpose.
__global__ __launch_bounds__(256) void k_out(const unsigned short* __restrict__ blob,
                                             const float* __restrict__ bn_scale,
                                             const float* __restrict__ bn_shift,
                                             const float4* __restrict__ updc4,
                                             float* __restrict__ out,
                                             float* __restrict__ upd) {
  __shared__ __align__(16) float tile[128 * 64];   // 32 KB
  int b = blockIdx.x;
  int wt = b & 3, h = (b >> 2) & 255, n = b >> 10;
  int w0 = wt * 64;
  int t = threadIdx.x;
  size_t pixbase = ((size_t)n * HH + h) * WW + w0;
  const float4* s4 = (const float4*)bn_scale;
  const float4* h4 = (const float4*)bn_shift;
#pragma unroll
  for (int iter = 0; iter < 4; ++iter) {
    int i = iter * 256 + t;
    int pix = i >> 4, cg = i & 15;
    u16x8 v = *(const u16x8*)(blob + ((pixbase + pix) << 7) + cg * 8);
    float4 sa = s4[cg * 2], sb = s4[cg * 2 + 1];
    float4 ha = h4[cg * 2], hb = h4[cg * 2 + 1];
    float f[8];
    f[0] = fmaxf(bf2f(v[0]) * sa.x + ha.x, 0.f);
    f[1] = fmaxf(bf2f(v[1]) * sa.y + ha.y, 0.f);
    f[2] = fmaxf(bf2f(v[2]) * sa.z + ha.z, 0.f);
    f[3] = fmaxf(bf2f(v[3]) * sa.w + ha.w, 0.f);
    f[4] = fmaxf(bf2f(v[4]) * sb.x + hb.x, 0.f);
    f[5] = fmaxf(bf2f(v[5]) * sb.y + hb.y, 0.f);
    f[6] = fmaxf(bf2f(v[6]) * sb.z + hb.z, 0.f);
    f[7] = fmaxf(bf2f(v[7]) * sb.w + hb.w, 0.f);
    int kk2 = (cg & 3) << 2;
#pragma unroll
    for (int e = 0; e < 8; ++e)
      tile[(cg * 8 + e) * 64 + (pix ^ kk2)] = f[e];
  }
  __syncthreads();
  int wq = t & 15, cc = t >> 4;
  float4 uq = updc4[(size_t)n * 16384 + (size_t)h * 64 + wt * 16 + wq];
#pragma unroll
  for (int i8 = 0; i8 < 8; ++i8) {
    int c = cc + i8 * 16;
    int kk = ((c >> 3) & 3) << 2;
    float4 v = *(const float4*)&tile[c * 64 + ((wq * 4) ^ kk)];
    size_t o = (((size_t)n * CO + c) * HH + h) * WW + w0 + wq * 4;
    *(float4*)(out + o) = v;
    *(float4*)(upd + o) = uq;
  }
}

extern "C" void kernel_launch(void* const* d_in, const int* in_sizes, int n_in,
                              void* d_out, int out_size, void* d_ws, size_t ws_size,
                              hipStream_t stream) {
  (void)in_sizes; (void)n_in; (void)out_size; (void)ws_size;
  const float* x     = (const float*)d_in[0];
  const float* mask  = (const float*)d_in[1];
  const float* W     = (const float*)d_in[2];
  const float* bias  = (const float*)d_in[3];
  const float* gamma = (const float*)d_in[4];
  const float* beta  = (const float*)d_in[5];

  float* out = (float*)d_out;                // output 0: 64M f32
  float* upd_out = out + 67108864;           // output 1: 64M f32

  // workspace layout (ws ~2 GiB per observed fills; we use < 224 MiB)
  char* wsb = (char*)d_ws;
  unsigned short* Wb = (unsigned short*)wsb;                  // 147,456 B
  float* msum     = (float*)(wsb + (2u << 20));               // 2 MB
  float* ratio    = (float*)(wsb + (4u << 20));               // 2 MB
  float* updc     = (float*)(wsb + (6u << 20));               // 2 MB
  float* bn_scale = (float*)(wsb + (8u << 20));               // 512 B
  float* bn_shift = bn_scale + 128;
  float* part_sum = (float*)(wsb + (9u << 20));               // 2 MB
  float* part_sq  = (float*)(wsb + (11u << 20));              // 2 MB
  unsigned short* xm   = (unsigned short*)(wsb + (16u << 20));  // 65 MB padded NHWC bf16
  unsigned short* blob = (unsigned short*)(wsb + (96u << 20));  // 128 MB NHWC bf16

  k_prep<<<321, 256, 0, stream>>>(W, Wb, xm);
  k_xm<<<8192, 256, 0, stream>>>((const float4*)x, (const float4*)mask, xm, (float4*)msum);
  k_update<<<2048, 256, 0, stream>>>(msum, ratio, updc);
  k_conv<<<4096, 256, 0, stream>>>(xm, Wb, ratio, updc, bias, blob, part_sum, part_sq);
  k_bnstats<<<128, 256, 0, stream>>>(part_sum, part_sq, gamma, beta, bn_scale, bn_shift);
  k_out<<<8192, 256, 0, stream>>>(blob, bn_scale, bn_shift, (const float4*)updc, out, upd_out);
}

// Round 5
// 343.638 us; speedup vs baseline: 1.6258x; 1.1687x over previous
//
#include <hip/hip_runtime.h>

typedef __attribute__((ext_vector_type(8))) short bf16x8;
typedef __attribute__((ext_vector_type(8))) unsigned short u16x8;
typedef __attribute__((ext_vector_type(4))) float f32x4;
typedef unsigned int u32;

#define CI 64
#define CO 128
#define HH 256
#define WW 256
#define HP 258
#define WP 258
#define SLIDE 576.0f

__device__ __forceinline__ unsigned short f2bf(float f) {
  union { float f; unsigned int u; } c; c.f = f;
  unsigned int u = c.u;
  return (unsigned short)((u + 0x7FFFu + ((u >> 16) & 1u)) >> 16);
}
__device__ __forceinline__ float bf2f(unsigned short h) {
  union { unsigned int u; float f; } c; c.u = ((unsigned int)h) << 16;
  return c.f;
}

// K_xm: blocks <8192: xm = bf16(x*mask) -> padded NHWC via LDS transpose; msum = sum_ci mask.
//       blocks >=8192: W -> Wb [kh][kw][co][ci] bf16 transpose, and xm border zeroing.
__global__ __launch_bounds__(256) void k_xm(const f32x4* __restrict__ x4,
                                            const f32x4* __restrict__ m4,
                                            unsigned short* __restrict__ xm,
                                            float4* __restrict__ msum4,
                                            const float* __restrict__ W,
                                            unsigned short* __restrict__ Wb) {
  __shared__ __align__(16) float tile[64 * 64 + 256];   // 16 KB tile + 1 KB reduce
  int b = blockIdx.x;
  int t = threadIdx.x;
  if (b >= 8192) {
    int blk = b - 8192;
    if (blk < 288) {
      int i = blk * 256 + t;            // exactly 9*128*64 = 73728
      int ci = i & 63, co = (i >> 6) & 127, tap = i >> 13;
      int kh = tap / 3, kw = tap - 3 * (tap / 3);
      Wb[i] = f2bf(W[((co * CI + ci) * 3 + kh) * 3 + kw]);
    } else {
      int i = (blk - 288) * 256 + t;    // 8 n * 1028 border pixels
      if (i >= 8 * 1028) return;
      int n = i / 1028, p = i - n * 1028;
      int hh, wp;
      if (p < 258) { hh = 0; wp = p; }
      else if (p < 516) { hh = 257; wp = p - 258; }
      else { int q = p - 516; hh = 1 + (q >> 1); wp = (q & 1) * 257; }
      u16x8 z = {0, 0, 0, 0, 0, 0, 0, 0};
      unsigned short* d = xm + (((size_t)n * HP + hh) * WP + wp) * CI;
#pragma unroll
      for (int k = 0; k < 8; ++k) *(u16x8*)(d + k * 8) = z;
    }
    return;
  }
  int wt = b & 3, h = (b >> 2) & 255, n = b >> 10;
  int w0 = wt * 64;
  int p4 = t & 15, chg = t >> 4;                         // px-quad, ch-group(4)
  size_t base = (size_t)n * CI * 16384 + (size_t)h * 64 + (w0 >> 2) + p4;
  float msx = 0.f, msy = 0.f, msz = 0.f, msw = 0.f;
#pragma unroll
  for (int j = 0; j < 4; ++j) {
    int ch = chg * 4 + j;
    size_t o = base + (size_t)ch * 16384;
    f32x4 xv = __builtin_nontemporal_load(&x4[o]);
    f32x4 mv = __builtin_nontemporal_load(&m4[o]);
    msx += mv.x; msy += mv.y; msz += mv.z; msw += mv.w;
    f32x4 pr = xv * mv;
    int kk = (ch >> 3) & 3;                              // XOR key (bits 2-3 of px idx)
    *(f32x4*)&tile[ch * 64 + ((p4 * 4) ^ (kk << 2))] = pr;
  }
  msx += __shfl_xor(msx, 16); msy += __shfl_xor(msy, 16);
  msz += __shfl_xor(msz, 16); msw += __shfl_xor(msw, 16);
  msx += __shfl_xor(msx, 32); msy += __shfl_xor(msy, 32);
  msz += __shfl_xor(msz, 32); msw += __shfl_xor(msw, 32);
  int wave = t >> 6, lane = t & 63;
  float4* red = (float4*)&tile[4096];
  if (lane < 16) red[wave * 16 + lane] = make_float4(msx, msy, msz, msw);
  __syncthreads();
  size_t dstb = (((size_t)n * HP + h + 1) * WP + (w0 + 1)) * CI;
#pragma unroll
  for (int iter = 0; iter < 2; ++iter) {
    int c = iter * 256 + t;
    int px = c >> 3, cg = c & 7;
    u16x8 v;
#pragma unroll
    for (int e = 0; e < 8; ++e) {
      int ch = cg * 8 + e;
      int kk = (ch >> 3) & 3;
      v[e] = f2bf(tile[ch * 64 + (px ^ (kk << 2))]);
    }
    *(u16x8*)(xm + dstb + (size_t)px * CI + cg * 8) = v;
  }
  if (t < 16) {
    float4 a = red[t], b2 = red[16 + t], c2 = red[32 + t], d2 = red[48 + t];
    float4 s;
    s.x = a.x + b2.x + c2.x + d2.x; s.y = a.y + b2.y + c2.y + d2.y;
    s.z = a.z + b2.z + c2.z + d2.z; s.w = a.w + b2.w + c2.w + d2.w;
    msum4[(size_t)n * 16384 + (size_t)h * 64 + (w0 >> 2) + t] = s;
  }
}

// K_conv: implicit-GEMM 3x3 conv, 128px x 128co per block, 4 waves, 16x16x32 bf16 MFMA.
// ratio/updc computed in-kernel from msum. Output: blob in NCHW bf16 (transposed in LDS).
__global__ __launch_bounds__(256) void k_conv(
    const unsigned short* __restrict__ xm, const unsigned short* __restrict__ Wb,
    const float* __restrict__ msum, const float* __restrict__ bias,
    unsigned short* __restrict__ blob, float* __restrict__ psum, float* __restrict__ psq) {
  __shared__ __align__(16) char lds[51472];  // 49920 staging (reused as tile) + lr/lu/cs
  int b = blockIdx.x;
  // XCD swizzle: each XCD owns one image n, h-contiguous -> row reuse in its L2
  int work = (b & 7) * 512 + (b >> 3);
  int wt = work & 1, h = (work >> 1) & 255, n = work >> 9;
  int w0 = wt * 128;
  int t = threadIdx.x;
  int lane = t & 63, wave = t >> 6;
  float* lr = (float*)(lds + 49920);   // ratio*clip per px (128)
  float* lu = (float*)(lds + 50432);   // clip(update) per px (128)
  float* cs = (float*)(lds + 50944);   // column sums (130)
  // stage 3 padded rows x 130 px x 64ch = 3120 16B chunks, swizzled source addr
#pragma unroll
  for (int iter = 0; iter < 12; ++iter) {
    int c = iter * 256 + t;
    int r = (c >= 2080) ? 2 : (c >= 1040 ? 1 : 0);
    int cc = c - r * 1040;
    int wslot = cc >> 3, sub = cc & 7;
    int srcc = (wslot << 3) + (sub ^ (wslot & 7));
    const unsigned short* g = xm + (((size_t)n * HP + h + r) * WP + w0) * CI + (size_t)srcc * 8;
    u32 ldsoff = (u32)(r * 16640 + (((iter * 256 + (wave << 6)) - r * 1040) << 4));
    __builtin_amdgcn_global_load_lds((const __attribute__((address_space(1))) u32*)g,
        (__attribute__((address_space(3))) u32*)(void*)(lds + ldsoff), 16, 0, 0);
  }
  if (t < 48) {   // tail: chunks 3072..3119 (all r=2)
    int c = 3072 + t;
    int cc = c - 2080;
    int wslot = cc >> 3, sub = cc & 7;
    int srcc = (wslot << 3) + (sub ^ (wslot & 7));
    const unsigned short* g = xm + (((size_t)n * HP + h + 2) * WP + w0) * CI + (size_t)srcc * 8;
    u32 ldsoff = (u32)(2 * 16640 + ((3072 - 2080) << 4));
    __builtin_amdgcn_global_load_lds((const __attribute__((address_space(1))) u32*)g,
        (__attribute__((address_space(3))) u32*)(void*)(lds + ldsoff), 16, 0, 0);
  }
  // column sums of mask-count for this strip (w0-1 .. w0+128)
  if (t < 130) {
    int w = w0 - 1 + t;
    float s = 0.f;
    if ((unsigned)w < 256u) {
      const float* mcol = msum + (size_t)n * 65536 + w;
      if (h >= 1) s += mcol[(h - 1) * 256];
      s += mcol[h * 256];
      if (h < 255) s += mcol[(h + 1) * 256];
    }
    cs[t] = s;
  }
  __syncthreads();
  if (t < 128) {
    float s = cs[t] + cs[t + 1] + cs[t + 2];
    float uc = fminf(s, 1.0f);
    lu[t] = uc;
    lr[t] = SLIDE / (s + 1e-6f) * uc;
  }

  int wm = wave >> 1, wn = wave & 1;
  int l15 = lane & 15, l4 = lane >> 4;
  f32x4 zero = {0.f, 0.f, 0.f, 0.f};
  f32x4 acc[4][4];
#pragma unroll
  for (int i = 0; i < 4; ++i)
#pragma unroll
    for (int j = 0; j < 4; ++j) acc[i][j] = zero;

#pragma unroll
  for (int kh = 0; kh < 3; ++kh) {
#pragma unroll
    for (int kw = 0; kw < 3; ++kw) {
      const unsigned short* wtap = Wb + ((kh * 3 + kw) * CO + wn * 64) * CI;
#pragma unroll
      for (int ks = 0; ks < 2; ++ks) {
        bf16x8 af[4], bfr[4];
#pragma unroll
        for (int mf = 0; mf < 4; ++mf) {
          int wslot = wm * 64 + mf * 16 + l15 + kw;
          int baddr = (((kh * 130 + wslot) << 7) + ks * 64 + l4 * 16) ^ ((wslot & 7) << 4);
          af[mf] = *(const bf16x8*)(lds + baddr);
        }
#pragma unroll
        for (int nf = 0; nf < 4; ++nf)
          bfr[nf] = *(const bf16x8*)(wtap + (nf * 16 + l15) * CI + ks * 32 + l4 * 8);
#pragma unroll
        for (int mf = 0; mf < 4; ++mf)
#pragma unroll
          for (int nf = 0; nf < 4; ++nf)
            acc[mf][nf] = __builtin_amdgcn_mfma_f32_16x16x32_bf16(af[mf], bfr[nf], acc[mf][nf], 0, 0, 0);
      }
    }
  }
  __syncthreads();   // staging area free; reuse as co-major output tile [co][128px]

  float bv[4];
#pragma unroll
  for (int nf = 0; nf < 4; ++nf) bv[nf] = bias[wn * 64 + nf * 16 + l15];
  float rs_s[4] = {0.f, 0.f, 0.f, 0.f}, rq_s[4] = {0.f, 0.f, 0.f, 0.f};
  int px0 = wm * 64 + l4 * 4;    // r2 packs 4 consecutive px
#pragma unroll
  for (int mf = 0; mf < 4; ++mf) {
    int pxb = px0 + mf * 16;
    float rs0 = lr[pxb], rs1 = lr[pxb + 1], rs2 = lr[pxb + 2], rs3 = lr[pxb + 3];
    float uc0 = lu[pxb], uc1 = lu[pxb + 1], uc2 = lu[pxb + 2], uc3 = lu[pxb + 3];
#pragma unroll
    for (int nf = 0; nf < 4; ++nf) {
      int co = wn * 64 + nf * 16 + l15;
      float v0 = acc[mf][nf][0] * rs0 + bv[nf] * uc0;
      float v1 = acc[mf][nf][1] * rs1 + bv[nf] * uc1;
      float v2 = acc[mf][nf][2] * rs2 + bv[nf] * uc2;
      float v3 = acc[mf][nf][3] * rs3 + bv[nf] * uc3;
      unsigned short h0 = f2bf(v0), h1 = f2bf(v1), h2 = f2bf(v2), h3 = f2bf(v3);
      float w0f = bf2f(h0), w1f = bf2f(h1), w2f = bf2f(h2), w3f = bf2f(h3);
      rs_s[nf] += w0f + w1f + w2f + w3f;
      rq_s[nf] += w0f * w0f + w1f * w1f + w2f * w2f + w3f * w3f;
      u32 lo = (u32)h0 | ((u32)h1 << 16);
      u32 hi = (u32)h2 | ((u32)h3 << 16);
      *(uint2*)(lds + co * 272 + pxb * 2) = make_uint2(lo, hi);
    }
  }
  float* sred = (float*)(lds + 34816);   // 512 floats (above tile's 34816 B)
#pragma unroll
  for (int nf = 0; nf < 4; ++nf) {
    float s = rs_s[nf], q = rq_s[nf];
    s += __shfl_xor(s, 16); s += __shfl_xor(s, 32);
    q += __shfl_xor(q, 16); q += __shfl_xor(q, 32);
    if (l4 == 0) {
      sred[(wave * 4 + nf) * 16 + l15] = s;
      sred[256 + (wave * 4 + nf) * 16 + l15] = q;
    }
  }
  __syncthreads();
  // blob store: NCHW bf16, 256B contiguous per 16 lanes
  int pixrow = (n * CO) << 16;
#pragma unroll
  for (int iter = 0; iter < 8; ++iter) {
    int i = iter * 256 + t;
    int co = i >> 4, oct = i & 15;
    u16x8 v = *(const u16x8*)(lds + co * 272 + oct * 16);
    *(u16x8*)(blob + (size_t)(pixrow + (co << 16) + (h << 8) + w0 + oct * 8)) = v;
  }
  int co = t & 127;
  int wn2 = co >> 6, nf2 = (co >> 4) & 3, cc2 = co & 15;
  float a0 = sred[(wn2 * 4 + nf2) * 16 + cc2] + sred[((2 + wn2) * 4 + nf2) * 16 + cc2];
  float a1 = sred[256 + (wn2 * 4 + nf2) * 16 + cc2] + sred[256 + ((2 + wn2) * 4 + nf2) * 16 + cc2];
  if (t < 128) psum[(size_t)b * 128 + co] = a0;
  else         psq[(size_t)b * 128 + co]  = a1;
}

// K_bnstats: reduce partials -> bn scale/shift
__global__ void k_bnstats(const float* __restrict__ psum, const float* __restrict__ psq,
                          const float* __restrict__ gamma, const float* __restrict__ beta,
                          float* __restrict__ bn_scale, float* __restrict__ bn_shift) {
  int co = blockIdx.x;
  int t = threadIdx.x;
  float s = 0.f, q = 0.f;
  for (int i = t; i < 4096; i += 256) {
    s += psum[(size_t)i * 128 + co];
    q += psq[(size_t)i * 128 + co];
  }
#pragma unroll
  for (int o = 1; o < 64; o <<= 1) { s += __shfl_xor(s, o); q += __shfl_xor(q, o); }
  __shared__ float red[8];
  int wv = t >> 6, ln = t & 63;
  if (ln == 0) { red[wv] = s; red[4 + wv] = q; }
  __syncthreads();
  if (t == 0) {
    s = red[0] + red[1] + red[2] + red[3];
    q = red[4] + red[5] + red[6] + red[7];
    const float inv = 1.0f / 524288.0f;
    float mean = s * inv;
    float var = q * inv - mean * mean;
    float sc = gamma[co] * rsqrtf(var + 1e-5f);
    bn_scale[co] = sc;
    bn_shift[co] = beta[co] - mean * sc;
  }
}

// K_out: pure streaming. Block = (n,h) row: updc row from msum in LDS, then
// blob (NCHW bf16) -> BN+ReLU -> out (f32 NCHW, nt) and upd broadcast (nt).
__global__ __launch_bounds__(256) void k_out(const unsigned short* __restrict__ blob,
                                             const float* __restrict__ msum,
                                             const float* __restrict__ bn_scale,
                                             const float* __restrict__ bn_shift,
                                             float* __restrict__ out,
                                             float* __restrict__ upd) {
  __shared__ float lu[256];
  __shared__ float cs[258];
  int b = blockIdx.x;
  int h = b & 255, n = b >> 8;
  int t = threadIdx.x;
  if (t < 258) {
    int w = t - 1;
    float s = 0.f;
    if ((unsigned)w < 256u) {
      const float* mcol = msum + (size_t)n * 65536 + w;
      if (h >= 1) s += mcol[(h - 1) * 256];
      s += mcol[h * 256];
      if (h < 255) s += mcol[(h + 1) * 256];
    }
    cs[t] = s;
  }
  __syncthreads();
  if (t < 256) lu[t] = fminf(cs[t] + cs[t + 1] + cs[t + 2], 1.0f);
  __syncthreads();
  size_t rowbase = ((size_t)(n * CO) << 16) + (h << 8);
#pragma unroll
  for (int iter = 0; iter < 32; ++iter) {
    int i = iter * 256 + t;               // 8192 = 128 c * 64 quads
    int c = i >> 6, q = i & 63;
    size_t off = rowbase + ((size_t)c << 16) + q * 4;
    uint2 raw = *(const uint2*)(blob + off);
    float sc = bn_scale[c], sh = bn_shift[c];
    f32x4 v;
    v.x = fmaxf(bf2f((unsigned short)(raw.x & 0xFFFF)) * sc + sh, 0.f);
    v.y = fmaxf(bf2f((unsigned short)(raw.x >> 16)) * sc + sh, 0.f);
    v.z = fmaxf(bf2f((unsigned short)(raw.y & 0xFFFF)) * sc + sh, 0.f);
    v.w = fmaxf(bf2f((unsigned short)(raw.y >> 16)) * sc + sh, 0.f);
    __builtin_nontemporal_store(v, (f32x4*)(out + off));
    f32x4 uv = *(const f32x4*)&lu[q * 4];
    __builtin_nontemporal_store(uv, (f32x4*)(upd + off));
  }
}

extern "C" void kernel_launch(void* const* d_in, const int* in_sizes, int n_in,
                              void* d_out, int out_size, void* d_ws, size_t ws_size,
                              hipStream_t stream) {
  (void)in_sizes; (void)n_in; (void)out_size; (void)ws_size;
  const float* x     = (const float*)d_in[0];
  const float* mask  = (const float*)d_in[1];
  const float* W     = (const float*)d_in[2];
  const float* bias  = (const float*)d_in[3];
  const float* gamma = (const float*)d_in[4];
  const float* beta  = (const float*)d_in[5];

  float* out = (float*)d_out;                // output 0: 64M f32
  float* upd_out = out + 67108864;           // output 1: 64M f32

  char* wsb = (char*)d_ws;
  unsigned short* Wb = (unsigned short*)wsb;                    // 147,456 B
  float* msum     = (float*)(wsb + (2u << 20));                 // 2 MB
  float* bn_scale = (float*)(wsb + (8u << 20));                 // 512 B
  float* bn_shift = bn_scale + 128;
  float* part_sum = (float*)(wsb + (9u << 20));                 // 2 MB
  float* part_sq  = (float*)(wsb + (11u << 20));                // 2 MB
  unsigned short* xm   = (unsigned short*)(wsb + (16u << 20));  // 65 MB padded NHWC bf16
  unsigned short* blob = (unsigned short*)(wsb + (96u << 20));  // 128 MB NCHW bf16

  k_xm<<<8513, 256, 0, stream>>>((const f32x4*)x, (const f32x4*)mask, xm,
                                 (float4*)msum, W, Wb);
  k_conv<<<4096, 256, 0, stream>>>(xm, Wb, msum, bias, blob, part_sum, part_sq);
  k_bnstats<<<128, 256, 0, stream>>>(part_sum, part_sq, gamma, beta, bn_scale, bn_shift);
  k_out<<<2048, 256, 0, stream>>>(blob, msum, bn_scale, bn_shift, out, upd_out);
}